// Round 2
// baseline (3519.047 us; speedup 1.0000x reference)
//
#include <hip/hip_runtime.h>
#include <stdint.h>

#define T_SEQ 512
#define BATCH 256
#define HID   128
#define G4    512   // 4*H
#define XD    257
#define ZD    16

// ---------- helpers ----------
__device__ __forceinline__ float bf2f(uint16_t u) {
  union { uint32_t i; float f; } v; v.i = ((uint32_t)u) << 16; return v.f;
}
__device__ __forceinline__ uint16_t f2bf(float f) {
  union { float f; uint32_t i; } v; v.f = f;
  uint32_t r = v.i + 0x7fffu + ((v.i >> 16) & 1u);
  return (uint16_t)(r >> 16);
}
__device__ __forceinline__ float tanhfast(float x) { return 2.0f / (1.0f + __expf(-2.0f * x)) - 1.0f; }
// unified gate activation: g==2 -> tanh, else sigmoid (no divergence)
__device__ __forceinline__ float gate_act(float pre, bool isg) {
  float s = isg ? (-2.0f * pre) : (-pre);
  float r = 1.0f / (1.0f + __expf(s));
  return isg ? (2.0f * r - 1.0f) : r;
}

// DPP quad_perm cross-lane (VALU pipe, not LDS): ctrl = sel0|sel1<<2|sel2<<4|sel3<<6
template <int C>
__device__ __forceinline__ float dppq(float x) {
  return __int_as_float(__builtin_amdgcn_mov_dpp(__float_as_int(x), C, 0xF, 0xF, true));
}
// ds_swizzle xor (LDS pipe) for xor masks that cross quads
template <int O>
__device__ __forceinline__ float swzx(float x) {
  return __int_as_float(__builtin_amdgcn_ds_swizzle(__float_as_int(x), O));
}

// quad transpose-reduce: lane s of each aligned quad holds partials a0..a3 (per gate,
// over its k-slice). Returns full sum for gate s on lane s. 3 DPP ops.
__device__ __forceinline__ float quad_reduce4(float a0, float a1, float a2, float a3, int g) {
  bool lb = (g & 1) != 0;
  float rl = dppq<0xB1>(lb ? a0 : a1);   // xor1: quad_perm [1,0,3,2]
  float rh = dppq<0xB1>(lb ? a2 : a3);
  float bl = (lb ? a1 : a0) + rl;        // gate (g&1), summed over slice pair
  float bh = (lb ? a3 : a2) + rh;        // gate (g&1)+2
  bool hb = (g & 2) != 0;
  float r2 = dppq<0x4E>(hb ? bl : bh);   // xor2: quad_perm [2,3,0,1]
  return (hb ? bh : bl) + r2;
}

// ---------- kernel 1: weight transposes ----------
__global__ void k_prep(const float* __restrict__ Wih_gx, const float* __restrict__ Wy,
                       float* __restrict__ wT, float* __restrict__ wyT) {
  int idx = blockIdx.x * 256 + threadIdx.x;
  const int N1 = XD * G4;          // 131584
  const int N2 = HID * XD;         // 32896
  if (idx < N1) {
    int j = idx & (G4 - 1), d = idx >> 9;       // wT[d*512+j] = Wih_gx[j*257+d]
    wT[idx] = Wih_gx[j * XD + d];
  } else if (idx < N1 + N2) {
    int i2 = idx - N1;
    int u = i2 / XD, d = i2 % XD;               // wyT[u*257+d] = Wy[d*128+u]
    wyT[i2] = Wy[d * HID + u];
  }
}

// ---------- kernel 2: px[t][b][j] = b_ih+b_hh + sum_d x[b][d][t]*Wih_gx[j][d] (bf16 out) ----------
__global__ __launch_bounds__(256) void k_proj(
    const float* __restrict__ x, const float* __restrict__ wT,
    const float* __restrict__ bih, const float* __restrict__ bhh,
    uint16_t* __restrict__ px) {
  __shared__ uint16_t xs[XD * 66];
  int tid = threadIdx.x;
  int t0 = blockIdx.x * 64, b = blockIdx.y;
  int lane = tid & 63;
  {
    int t = tid & 63, d0 = tid >> 6;
    for (int d = d0; d < XD; d += 4)
      xs[d * 66 + t] = f2bf(x[((size_t)b * XD + d) * T_SEQ + t0 + t]);
  }
  __syncthreads();
  int w = __builtin_amdgcn_readfirstlane(tid >> 6);
  for (int p = 0; p < 8; ++p) {
    int j0 = w * 128 + p * 16;
    float acc[16];
#pragma unroll
    for (int i = 0; i < 16; ++i) acc[i] = bih[j0 + i] + bhh[j0 + i];
    for (int d = 0; d < XD; ++d) {
      float xv = bf2f(xs[d * 66 + lane]);
      const float* wrow = wT + (size_t)d * G4 + j0;
#pragma unroll
      for (int i = 0; i < 16; ++i) acc[i] = fmaf(wrow[i], xv, acc[i]);
    }
    size_t base = ((size_t)(t0 + lane) * BATCH + b) * G4 + j0;
    uint32_t pk[8];
#pragma unroll
    for (int i = 0; i < 8; ++i)
      pk[i] = (uint32_t)f2bf(acc[2 * i]) | ((uint32_t)f2bf(acc[2 * i + 1]) << 16);
    uint4* dst = (uint4*)(px + base);
    dst[0] = make_uint4(pk[0], pk[1], pk[2], pk[3]);
    dst[1] = make_uint4(pk[4], pk[5], pk[6], pk[7]);
  }
}

// ---------- kernel 3: backward LSTM g_x — slice-split quad, 8 b128 reads/step ----------
// launch_bounds(512,1): grid == 1 block/CU always; cap VGPRs at 256 so the
// 128 persistent weight floats/thread stay in registers (at (512,2) they spilled).
__global__ __launch_bounds__(512, 1) void k_lstm_gx(
    const uint16_t* __restrict__ px, const float* __restrict__ Whh,
    uint16_t* __restrict__ gx) {
  __shared__ __align__(128) float hl[2][HID];
  int tid = threadIdx.x, b = blockIdx.x;
  int u = tid >> 2, g = tid & 3;
  int j = g * HID + u;                  // gate row this thread owns (for px/bias)
  int rot = g << 1, hbase = g << 3;     // XOR-stagger so 4 g-segments hit disjoint banks
  // wA[q][4n+c] = Whh[(q*128+u)*128 + g*32 + (n^rot)*4 + c]  (pre-rotated storage)
  float wA[4][32];
#pragma unroll
  for (int q = 0; q < 4; ++q)
#pragma unroll
    for (int n = 0; n < 8; ++n) {
      int i = n ^ rot;
      float4 wv = *(const float4*)(Whh + ((size_t)(q * HID + u)) * HID + g * 32 + i * 4);
      wA[q][4 * n + 0] = wv.x; wA[q][4 * n + 1] = wv.y;
      wA[q][4 * n + 2] = wv.z; wA[q][4 * n + 3] = wv.w;
    }
  if (tid < HID) hl[0][tid] = 0.0f;
  float c = 0.0f;
  int cur = 0;
  bool isg = (g == 2);
  uint16_t pcur = px[((size_t)(T_SEQ - 1) * BATCH + b) * G4 + j];
  __syncthreads();
  for (int t = T_SEQ - 1; t >= 0; --t) {
    int tn = t > 0 ? t - 1 : 0;
    uint16_t pnext = px[((size_t)tn * BATCH + b) * G4 + j];
    const float4* h4 = (const float4*)hl[cur];
    float a0 = 0.f, a1 = 0.f, a2 = 0.f, a3 = 0.f;
#pragma unroll
    for (int n = 0; n < 8; ++n) {
      float4 hv = h4[hbase + (n ^ rot)];
      a0 = fmaf(wA[0][4 * n + 0], hv.x, a0); a0 = fmaf(wA[0][4 * n + 1], hv.y, a0);
      a0 = fmaf(wA[0][4 * n + 2], hv.z, a0); a0 = fmaf(wA[0][4 * n + 3], hv.w, a0);
      a1 = fmaf(wA[1][4 * n + 0], hv.x, a1); a1 = fmaf(wA[1][4 * n + 1], hv.y, a1);
      a1 = fmaf(wA[1][4 * n + 2], hv.z, a1); a1 = fmaf(wA[1][4 * n + 3], hv.w, a1);
      a2 = fmaf(wA[2][4 * n + 0], hv.x, a2); a2 = fmaf(wA[2][4 * n + 1], hv.y, a2);
      a2 = fmaf(wA[2][4 * n + 2], hv.z, a2); a2 = fmaf(wA[2][4 * n + 3], hv.w, a2);
      a3 = fmaf(wA[3][4 * n + 0], hv.x, a3); a3 = fmaf(wA[3][4 * n + 1], hv.y, a3);
      a3 = fmaf(wA[3][4 * n + 2], hv.z, a3); a3 = fmaf(wA[3][4 * n + 3], hv.w, a3);
    }
    float pre = quad_reduce4(a0, a1, a2, a3, g) + bf2f(pcur);
    float act = gate_act(pre, isg);
    float af = dppq<0x55>(act);   // quad lane 1 (f)
    float ag = dppq<0xAA>(act);   // quad lane 2 (g)
    float ao = dppq<0xFF>(act);   // quad lane 3 (o)
    if (g == 0) {
      c = af * c + act * ag;
      float h = ao * tanhfast(c);
      hl[cur ^ 1][u] = h;
      gx[((size_t)t * BATCH + b) * HID + u] = f2bf(h);
    }
    cur ^= 1;
    pcur = pnext;
    __syncthreads();
  }
}

// ---------- kernel 4: fused inference — slice-split stages, DPP reduces ----------
// launch_bounds(512,1): ~216 persistent weight floats/thread need the 256-VGPR cap.
__global__ __launch_bounds__(512, 1) void k_inf(
    const uint16_t* __restrict__ gx, const float* __restrict__ eps,
    const float* __restrict__ Wih_gz, const float* __restrict__ Whh_gz,
    const float* __restrict__ bih_gz, const float* __restrict__ bhh_gz,
    const float* __restrict__ W0, const float* __restrict__ b0,
    const float* __restrict__ Wm, const float* __restrict__ bm,
    const float* __restrict__ Wv, const float* __restrict__ bv,
    float* __restrict__ zbuf, float* __restrict__ out_mean,
    float* __restrict__ out_logvar, float* __restrict__ out_z) {
  __shared__ __align__(128) float gxl[HID];
  __shared__ __align__(128) float gzl[2][HID];
  __shared__ __align__(128) float hvec[16 * 12];   // padded: h[8m+k] at [12m+k] (bank-spread)
  __shared__ __align__(128) float zl[ZD];
  int tid = threadIdx.x, b = blockIdx.x;
  // ---- stage A layout: quad (u, gate g), 32-slice of [z(16)|h(128)] per lane ----
  int u = tid >> 2, g = tid & 3;
  int j = g * HID + u;
  int rot = g << 1, hbase = g << 3;
  float wA[4][32];
  float4 wz[4];
#pragma unroll
  for (int q = 0; q < 4; ++q) {
#pragma unroll
    for (int n = 0; n < 8; ++n) {
      int i = n ^ rot;
      float4 wv = *(const float4*)(Whh_gz + ((size_t)(q * HID + u)) * HID + g * 32 + i * 4);
      wA[q][4 * n + 0] = wv.x; wA[q][4 * n + 1] = wv.y;
      wA[q][4 * n + 2] = wv.z; wA[q][4 * n + 3] = wv.w;
    }
    wz[q] = *(const float4*)(Wih_gz + (size_t)(q * HID + u) * ZD + g * 4);
  }
  float bzr = bih_gz[j] + bhh_gz[j];
  // ---- stage B layout: 8-way slice, 2 outputs per thread ----
  int sB = tid & 7, uB = (tid >> 3) << 1;
  float w0a[32], w0b[32];
#pragma unroll
  for (int n = 0; n < 8; ++n) {
    int i = n ^ sB;
    float4 va = *(const float4*)(W0 + (size_t)uB * 256 + sB * 32 + i * 4);
    float4 vb = *(const float4*)(W0 + (size_t)(uB + 1) * 256 + sB * 32 + i * 4);
    w0a[4 * n + 0] = va.x; w0a[4 * n + 1] = va.y; w0a[4 * n + 2] = va.z; w0a[4 * n + 3] = va.w;
    w0b[4 * n + 0] = vb.x; w0b[4 * n + 1] = vb.y; w0b[4 * n + 2] = vb.z; w0b[4 * n + 3] = vb.w;
  }
  float b0a = b0[uB], b0b = b0[uB + 1];
  // ---- stage C layout: 32 lanes per output o; lanes 0-15 mean, 16-31 logvar ----
  int o = tid >> 5, lo = tid & 31;
  float wmr[8];
  {
    const float* Wsel = (lo < 16) ? (Wm + (size_t)o * HID + (lo & 15) * 8)
                                  : (Wv + (size_t)o * HID + (lo & 15) * 8);
#pragma unroll
    for (int i = 0; i < 8; ++i) wmr[i] = Wsel[i];
  }
  float bmr = bm[o], bvr = bv[o];
  float czr = 0.0f;
  int cur = 0;
  bool isg = (g == 2);
  if (tid < HID) {
    gzl[0][tid] = 0.0f;
    gxl[tid] = bf2f(gx[(size_t)b * HID + tid]);
  }
  float epcur = (lo == 0) ? eps[(size_t)b * ZD + o] : 0.0f;
  __syncthreads();
  for (int t = 0; t < T_SEQ; ++t) {
    int tn = (t < T_SEQ - 1) ? t + 1 : t;
    float gxnext = (tid < HID) ? bf2f(gx[((size_t)tn * BATCH + b) * HID + tid]) : 0.0f;
    float epnext = (lo == 0) ? eps[((size_t)tn * BATCH + b) * ZD + o] : 0.0f;
    // ---- stage B: h = tanh([gx, gz] @ W0.T + b0), 8-way slice + 8-lane all-reduce ----
    {
      const float4* seg = (sB < 4) ? ((const float4*)gxl + (sB << 3))
                                   : ((const float4*)(gzl[cur]) + ((sB - 4) << 3));
      float pa = 0.f, pb = 0.f;
#pragma unroll
      for (int n = 0; n < 8; ++n) {
        float4 v = seg[n ^ sB];
        pa = fmaf(w0a[4 * n + 0], v.x, pa); pa = fmaf(w0a[4 * n + 1], v.y, pa);
        pa = fmaf(w0a[4 * n + 2], v.z, pa); pa = fmaf(w0a[4 * n + 3], v.w, pa);
        pb = fmaf(w0b[4 * n + 0], v.x, pb); pb = fmaf(w0b[4 * n + 1], v.y, pb);
        pb = fmaf(w0b[4 * n + 2], v.z, pb); pb = fmaf(w0b[4 * n + 3], v.w, pb);
      }
      pa += dppq<0xB1>(pa); pa += dppq<0x4E>(pa); pa += swzx<0x101F>(pa);
      pb += dppq<0xB1>(pb); pb += dppq<0x4E>(pb); pb += swzx<0x101F>(pb);
      if (sB == 0) {
        hvec[((uB >> 3) * 12) + (uB & 7)] = tanhfast(pa + b0a);
        int u1 = uB + 1;
        hvec[((u1 >> 3) * 12) + (u1 & 7)] = tanhfast(pb + b0b);
      }
    }
    __syncthreads();  // b1
    // ---- stage C: mean/logvar/z fused, weights in VGPRs ----
    {
      int m = lo & 15;
      const float4* hh = (const float4*)(hvec + m * 12);
      float4 h0 = hh[0], h1 = hh[1];
      float p = wmr[0] * h0.x + wmr[1] * h0.y + wmr[2] * h0.z + wmr[3] * h0.w +
                wmr[4] * h1.x + wmr[5] * h1.y + wmr[6] * h1.z + wmr[7] * h1.w;
      p += dppq<0xB1>(p);
      p += dppq<0x4E>(p);
      p += swzx<0x101F>(p);
      p += swzx<0x201F>(p);
      float other = swzx<0x401F>(p);   // lanes 0-15 get logvar sum, 16-31 get mean sum
      if (lo == 0) {
        float mean = p + bmr;
        float lv = other + bvr;
        float zv = epcur * __expf(0.5f * lv) + mean;
        zl[o] = zv;
        out_mean[((size_t)b * ZD + o) * T_SEQ + t] = mean;
        out_logvar[((size_t)b * ZD + o) * T_SEQ + t] = lv;
        out_z[((size_t)b * ZD + o) * T_SEQ + t] = zv;
        zbuf[((size_t)t * BATCH + b) * ZD + o] = zv;
      }
    }
    __syncthreads();  // b2
    // ---- stage A: g_z LSTM cell, slice-split quad + butterfly reduce ----
    {
      float4 zv = ((const float4*)zl)[g];
      float a0 = wz[0].x * zv.x; a0 = fmaf(wz[0].y, zv.y, a0);
      a0 = fmaf(wz[0].z, zv.z, a0); a0 = fmaf(wz[0].w, zv.w, a0);
      float a1 = wz[1].x * zv.x; a1 = fmaf(wz[1].y, zv.y, a1);
      a1 = fmaf(wz[1].z, zv.z, a1); a1 = fmaf(wz[1].w, zv.w, a1);
      float a2 = wz[2].x * zv.x; a2 = fmaf(wz[2].y, zv.y, a2);
      a2 = fmaf(wz[2].z, zv.z, a2); a2 = fmaf(wz[2].w, zv.w, a2);
      float a3 = wz[3].x * zv.x; a3 = fmaf(wz[3].y, zv.y, a3);
      a3 = fmaf(wz[3].z, zv.z, a3); a3 = fmaf(wz[3].w, zv.w, a3);
      const float4* h4 = (const float4*)gzl[cur];
#pragma unroll
      for (int n = 0; n < 8; ++n) {
        float4 hv = h4[hbase + (n ^ rot)];
        a0 = fmaf(wA[0][4 * n + 0], hv.x, a0); a0 = fmaf(wA[0][4 * n + 1], hv.y, a0);
        a0 = fmaf(wA[0][4 * n + 2], hv.z, a0); a0 = fmaf(wA[0][4 * n + 3], hv.w, a0);
        a1 = fmaf(wA[1][4 * n + 0], hv.x, a1); a1 = fmaf(wA[1][4 * n + 1], hv.y, a1);
        a1 = fmaf(wA[1][4 * n + 2], hv.z, a1); a1 = fmaf(wA[1][4 * n + 3], hv.w, a1);
        a2 = fmaf(wA[2][4 * n + 0], hv.x, a2); a2 = fmaf(wA[2][4 * n + 1], hv.y, a2);
        a2 = fmaf(wA[2][4 * n + 2], hv.z, a2); a2 = fmaf(wA[2][4 * n + 3], hv.w, a2);
        a3 = fmaf(wA[3][4 * n + 0], hv.x, a3); a3 = fmaf(wA[3][4 * n + 1], hv.y, a3);
        a3 = fmaf(wA[3][4 * n + 2], hv.z, a3); a3 = fmaf(wA[3][4 * n + 3], hv.w, a3);
      }
      float pre = quad_reduce4(a0, a1, a2, a3, g) + bzr;
      float act = gate_act(pre, isg);
      float af = dppq<0x55>(act);
      float ag = dppq<0xAA>(act);
      float ao = dppq<0xFF>(act);
      if (g == 0) {
        czr = af * czr + act * ag;
        gzl[cur ^ 1][u] = ao * tanhfast(czr);
      }
      if (tid < HID) gxl[tid] = gxnext;
    }
    epcur = epnext;
    cur ^= 1;
    __syncthreads();  // b3
  }
}

// ---------- kernel 5: decoder LSTM — slice-split quad ----------
// launch_bounds(512,1): ~150 persistent weight floats/thread need >128 VGPRs.
__global__ __launch_bounds__(512, 1) void k_dec(
    const float* __restrict__ zbuf, const float* __restrict__ Wih_h,
    const float* __restrict__ Whh_h, const float* __restrict__ bih,
    const float* __restrict__ bhh, uint16_t* __restrict__ hdec) {
  __shared__ __align__(128) float hl[2][HID];
  __shared__ __align__(128) float zls[2][ZD];
  int tid = threadIdx.x, b = blockIdx.x;
  int u = tid >> 2, g = tid & 3;
  int j = g * HID + u;
  int rot = g << 1, hbase = g << 3;
  float wA[4][32];
  float4 wz[4];
#pragma unroll
  for (int q = 0; q < 4; ++q) {
#pragma unroll
    for (int n = 0; n < 8; ++n) {
      int i = n ^ rot;
      float4 wv = *(const float4*)(Whh_h + ((size_t)(q * HID + u)) * HID + g * 32 + i * 4);
      wA[q][4 * n + 0] = wv.x; wA[q][4 * n + 1] = wv.y;
      wA[q][4 * n + 2] = wv.z; wA[q][4 * n + 3] = wv.w;
    }
    wz[q] = *(const float4*)(Wih_h + (size_t)(q * HID + u) * ZD + g * 4);
  }
  float bz = bih[j] + bhh[j];
  if (tid < HID) hl[0][tid] = 0.0f;
  if (tid < ZD) zls[0][tid] = zbuf[(size_t)b * ZD + tid];
  float c = 0.0f;
  int cur = 0;
  bool isg = (g == 2);
  __syncthreads();
  for (int t = 0; t < T_SEQ; ++t) {
    int tn = (t < T_SEQ - 1) ? t + 1 : t;
    float znext = (tid < ZD) ? zbuf[((size_t)tn * BATCH + b) * ZD + tid] : 0.0f;
    float4 zv = ((const float4*)zls[cur])[g];
    float a0 = wz[0].x * zv.x; a0 = fmaf(wz[0].y, zv.y, a0);
    a0 = fmaf(wz[0].z, zv.z, a0); a0 = fmaf(wz[0].w, zv.w, a0);
    float a1 = wz[1].x * zv.x; a1 = fmaf(wz[1].y, zv.y, a1);
    a1 = fmaf(wz[1].z, zv.z, a1); a1 = fmaf(wz[1].w, zv.w, a1);
    float a2 = wz[2].x * zv.x; a2 = fmaf(wz[2].y, zv.y, a2);
    a2 = fmaf(wz[2].z, zv.z, a2); a2 = fmaf(wz[2].w, zv.w, a2);
    float a3 = wz[3].x * zv.x; a3 = fmaf(wz[3].y, zv.y, a3);
    a3 = fmaf(wz[3].z, zv.z, a3); a3 = fmaf(wz[3].w, zv.w, a3);
    const float4* h4 = (const float4*)hl[cur];
#pragma unroll
    for (int n = 0; n < 8; ++n) {
      float4 hv = h4[hbase + (n ^ rot)];
      a0 = fmaf(wA[0][4 * n + 0], hv.x, a0); a0 = fmaf(wA[0][4 * n + 1], hv.y, a0);
      a0 = fmaf(wA[0][4 * n + 2], hv.z, a0); a0 = fmaf(wA[0][4 * n + 3], hv.w, a0);
      a1 = fmaf(wA[1][4 * n + 0], hv.x, a1); a1 = fmaf(wA[1][4 * n + 1], hv.y, a1);
      a1 = fmaf(wA[1][4 * n + 2], hv.z, a1); a1 = fmaf(wA[1][4 * n + 3], hv.w, a1);
      a2 = fmaf(wA[2][4 * n + 0], hv.x, a2); a2 = fmaf(wA[2][4 * n + 1], hv.y, a2);
      a2 = fmaf(wA[2][4 * n + 2], hv.z, a2); a2 = fmaf(wA[2][4 * n + 3], hv.w, a2);
      a3 = fmaf(wA[3][4 * n + 0], hv.x, a3); a3 = fmaf(wA[3][4 * n + 1], hv.y, a3);
      a3 = fmaf(wA[3][4 * n + 2], hv.z, a3); a3 = fmaf(wA[3][4 * n + 3], hv.w, a3);
    }
    float pre = quad_reduce4(a0, a1, a2, a3, g) + bz;
    float act = gate_act(pre, isg);
    float af = dppq<0x55>(act);
    float ag = dppq<0xAA>(act);
    float ao = dppq<0xFF>(act);
    if (g == 0) {
      c = af * c + act * ag;
      float h = ao * tanhfast(c);
      hl[cur ^ 1][u] = h;
      hdec[((size_t)t * BATCH + b) * HID + u] = f2bf(h);
    }
    if (tid < ZD) zls[cur ^ 1][tid] = znext;
    cur ^= 1;
    __syncthreads();
  }
}

// ---------- kernel 6: y = exp(hdec @ Wy.T + by), output (B, 257, T) ----------
__global__ __launch_bounds__(256) void k_y(
    const uint16_t* __restrict__ hdec, const float* __restrict__ wyT,
    const float* __restrict__ by, float* __restrict__ out_y) {
  __shared__ __align__(16) float hl[HID * 65];
  int tid = threadIdx.x;
  int t0 = blockIdx.x * 64, b = blockIdx.y;
  {
    int uu = tid & 127, tg = tid >> 7;
    for (int tt = tg; tt < 64; tt += 2)
      hl[uu * 65 + tt] = bf2f(hdec[((size_t)(t0 + tt) * BATCH + b) * HID + uu]);
  }
  __syncthreads();
  int w = __builtin_amdgcn_readfirstlane(tid >> 6);
  int lane = tid & 63;
  for (int p = 0; p < 4; ++p) {
    int d0 = w * 16 + p * 64;
    float acc[16];
#pragma unroll
    for (int i = 0; i < 16; ++i) acc[i] = by[d0 + i];
    for (int uu = 0; uu < HID; ++uu) {
      float hv = hl[uu * 65 + lane];
      const float* wrow = wyT + (size_t)uu * XD + d0;
#pragma unroll
      for (int i = 0; i < 16; ++i) acc[i] = fmaf(wrow[i], hv, acc[i]);
    }
#pragma unroll
    for (int i = 0; i < 16; ++i)
      out_y[((size_t)b * XD + d0 + i) * T_SEQ + t0 + lane] = __expf(acc[i]);
  }
  if (w == 0) {  // d = 256 tail
    float acc = by[256];
    for (int uu = 0; uu < HID; ++uu)
      acc = fmaf(wyT[(size_t)uu * XD + 256], hl[uu * 65 + lane], acc);
    out_y[((size_t)b * XD + 256) * T_SEQ + t0 + lane] = __expf(acc);
  }
}

extern "C" void kernel_launch(void* const* d_in, const int* in_sizes, int n_in,
                              void* d_out, int out_size, void* d_ws, size_t ws_size,
                              hipStream_t stream) {
  const float* x      = (const float*)d_in[0];
  const float* eps    = (const float*)d_in[1];
  const float* Wih_gx = (const float*)d_in[2];
  const float* Whh_gx = (const float*)d_in[3];
  const float* bih_gx = (const float*)d_in[4];
  const float* bhh_gx = (const float*)d_in[5];
  const float* Wih_gz = (const float*)d_in[6];
  const float* Whh_gz = (const float*)d_in[7];
  const float* bih_gz = (const float*)d_in[8];
  const float* bhh_gz = (const float*)d_in[9];
  const float* W0     = (const float*)d_in[10];
  const float* b0     = (const float*)d_in[11];
  const float* Wm     = (const float*)d_in[12];
  const float* bm     = (const float*)d_in[13];
  const float* Wv     = (const float*)d_in[14];
  const float* bv     = (const float*)d_in[15];
  const float* Wih_h  = (const float*)d_in[16];
  const float* Whh_h  = (const float*)d_in[17];
  const float* bih_h  = (const float*)d_in[18];
  const float* bhh_h  = (const float*)d_in[19];
  const float* Wy     = (const float*)d_in[20];
  const float* by     = (const float*)d_in[21];

  char* ws = (char*)d_ws;
  float*    wT   = (float*)(ws + 0);                       // 257*512 f32   = 526,336 B
  float*    wyT  = (float*)(ws + 526336);                  // 128*257 f32   = 131,584 B
  uint16_t* px   = (uint16_t*)(ws + (1u << 20));           // bf16 T*B*512  = 134,217,728 B
  uint16_t* gx   = (uint16_t*)(ws + 135266304);            // bf16 T*B*128  =  33,554,432 B
  float*    zbuf = (float*)(ws + 168820736);               // f32  T*B*16   =   8,388,608 B
  uint16_t* hdec = (uint16_t*)(ws + 177209344);            // bf16 T*B*128  =  33,554,432 B

  float* out_y      = (float*)d_out;                         // (B,257,T)
  float* out_mean   = out_y + (size_t)BATCH * XD * T_SEQ;    // (B,16,T)
  float* out_logvar = out_mean + (size_t)BATCH * ZD * T_SEQ;
  float* out_z      = out_logvar + (size_t)BATCH * ZD * T_SEQ;

  k_prep<<<dim3(643), dim3(256), 0, stream>>>(Wih_gx, Wy, wT, wyT);
  k_proj<<<dim3(8, 256), dim3(256), 0, stream>>>(x, wT, bih_gx, bhh_gx, px);
  k_lstm_gx<<<dim3(256), dim3(512), 0, stream>>>(px, Whh_gx, gx);
  k_inf<<<dim3(256), dim3(512), 0, stream>>>(gx, eps, Wih_gz, Whh_gz, bih_gz, bhh_gz,
                                             W0, b0, Wm, bm, Wv, bv,
                                             zbuf, out_mean, out_logvar, out_z);
  k_dec<<<dim3(256), dim3(512), 0, stream>>>(zbuf, Wih_h, Whh_h, bih_h, bhh_h, hdec);
  k_y<<<dim3(8, 256), dim3(256), 0, stream>>>(hdec, wyT, by, out_y);
}

// Round 3
// 3428.910 us; speedup vs baseline: 1.0263x; 1.0263x over previous
//
#include <hip/hip_runtime.h>
#include <stdint.h>

#define T_SEQ 512
#define BATCH 256
#define HID   128
#define G4    512   // 4*H
#define XD    257
#define ZD    16

// ---------- helpers ----------
__device__ __forceinline__ float bf2f(uint16_t u) {
  union { uint32_t i; float f; } v; v.i = ((uint32_t)u) << 16; return v.f;
}
__device__ __forceinline__ uint16_t f2bf(float f) {
  union { float f; uint32_t i; } v; v.f = f;
  uint32_t r = v.i + 0x7fffu + ((v.i >> 16) & 1u);
  return (uint16_t)(r >> 16);
}
__device__ __forceinline__ float tanhfast(float x) { return 2.0f / (1.0f + __expf(-2.0f * x)) - 1.0f; }
// unified gate activation: g==2 -> tanh, else sigmoid (no divergence)
__device__ __forceinline__ float gate_act(float pre, bool isg) {
  float s = isg ? (-2.0f * pre) : (-pre);
  float r = 1.0f / (1.0f + __expf(s));
  return isg ? (2.0f * r - 1.0f) : r;
}

// Pin a value into a VGPR: opaque def the compiler cannot rematerialize.
// Without this, LLVM sinks the (loop-invariant) weight loads INTO the timestep
// loop, re-reading ~440 KB/CU/step from L1/L2 (measured: VGPR_Count stuck at
// 128 and k_inf L1-BW-bound at ~6700 cyc/step).
#define PIN(x) asm volatile("" : "+v"(x))

// DPP quad_perm cross-lane (VALU pipe, not LDS): ctrl = sel0|sel1<<2|sel2<<4|sel3<<6
template <int C>
__device__ __forceinline__ float dppq(float x) {
  return __int_as_float(__builtin_amdgcn_mov_dpp(__float_as_int(x), C, 0xF, 0xF, true));
}
// ds_swizzle xor (LDS pipe) for xor masks that cross quads
template <int O>
__device__ __forceinline__ float swzx(float x) {
  return __int_as_float(__builtin_amdgcn_ds_swizzle(__float_as_int(x), O));
}

// quad transpose-reduce: lane s of each aligned quad holds partials a0..a3 (per gate,
// over its k-slice). Returns full sum for gate s on lane s. 3 DPP ops.
__device__ __forceinline__ float quad_reduce4(float a0, float a1, float a2, float a3, int g) {
  bool lb = (g & 1) != 0;
  float rl = dppq<0xB1>(lb ? a0 : a1);   // xor1: quad_perm [1,0,3,2]
  float rh = dppq<0xB1>(lb ? a2 : a3);
  float bl = (lb ? a1 : a0) + rl;        // gate (g&1), summed over slice pair
  float bh = (lb ? a3 : a2) + rh;        // gate (g&1)+2
  bool hb = (g & 2) != 0;
  float r2 = dppq<0x4E>(hb ? bl : bh);   // xor2: quad_perm [2,3,0,1]
  return (hb ? bh : bl) + r2;
}

// ---------- kernel 1: weight transposes ----------
__global__ void k_prep(const float* __restrict__ Wih_gx, const float* __restrict__ Wy,
                       float* __restrict__ wT, float* __restrict__ wyT) {
  int idx = blockIdx.x * 256 + threadIdx.x;
  const int N1 = XD * G4;          // 131584
  const int N2 = HID * XD;         // 32896
  if (idx < N1) {
    int j = idx & (G4 - 1), d = idx >> 9;       // wT[d*512+j] = Wih_gx[j*257+d]
    wT[idx] = Wih_gx[j * XD + d];
  } else if (idx < N1 + N2) {
    int i2 = idx - N1;
    int u = i2 / XD, d = i2 % XD;               // wyT[u*257+d] = Wy[d*128+u]
    wyT[i2] = Wy[d * HID + u];
  }
}

// ---------- kernel 2: px[t][b][j] = b_ih+b_hh + sum_d x[b][d][t]*Wih_gx[j][d] (bf16 out) ----------
__global__ __launch_bounds__(256) void k_proj(
    const float* __restrict__ x, const float* __restrict__ wT,
    const float* __restrict__ bih, const float* __restrict__ bhh,
    uint16_t* __restrict__ px) {
  __shared__ uint16_t xs[XD * 66];
  int tid = threadIdx.x;
  int t0 = blockIdx.x * 64, b = blockIdx.y;
  int lane = tid & 63;
  {
    int t = tid & 63, d0 = tid >> 6;
    for (int d = d0; d < XD; d += 4)
      xs[d * 66 + t] = f2bf(x[((size_t)b * XD + d) * T_SEQ + t0 + t]);
  }
  __syncthreads();
  int w = __builtin_amdgcn_readfirstlane(tid >> 6);
  for (int p = 0; p < 8; ++p) {
    int j0 = w * 128 + p * 16;
    float acc[16];
#pragma unroll
    for (int i = 0; i < 16; ++i) acc[i] = bih[j0 + i] + bhh[j0 + i];
    for (int d = 0; d < XD; ++d) {
      float xv = bf2f(xs[d * 66 + lane]);
      const float* wrow = wT + (size_t)d * G4 + j0;
#pragma unroll
      for (int i = 0; i < 16; ++i) acc[i] = fmaf(wrow[i], xv, acc[i]);
    }
    size_t base = ((size_t)(t0 + lane) * BATCH + b) * G4 + j0;
    uint32_t pk[8];
#pragma unroll
    for (int i = 0; i < 8; ++i)
      pk[i] = (uint32_t)f2bf(acc[2 * i]) | ((uint32_t)f2bf(acc[2 * i + 1]) << 16);
    uint4* dst = (uint4*)(px + base);
    dst[0] = make_uint4(pk[0], pk[1], pk[2], pk[3]);
    dst[1] = make_uint4(pk[4], pk[5], pk[6], pk[7]);
  }
}

// ---------- kernel 3: backward LSTM g_x — slice-split quad, weights pinned in VGPRs ----------
__global__ __launch_bounds__(512, 1) void k_lstm_gx(
    const uint16_t* __restrict__ px, const float* __restrict__ Whh,
    uint16_t* __restrict__ gx) {
  __shared__ __align__(128) float hl[2][HID];
  int tid = threadIdx.x, b = blockIdx.x;
  int u = tid >> 2, g = tid & 3;
  int j = g * HID + u;                  // gate row this thread owns (for px/bias)
  int rot = g << 1, hbase = g << 3;     // XOR-stagger so 4 g-segments hit disjoint banks
  // wA[q][4n+c] = Whh[(q*128+u)*128 + g*32 + (n^rot)*4 + c]  (pre-rotated storage)
  float wA[4][32];
#pragma unroll
  for (int q = 0; q < 4; ++q)
#pragma unroll
    for (int n = 0; n < 8; ++n) {
      int i = n ^ rot;
      float4 wv = *(const float4*)(Whh + ((size_t)(q * HID + u)) * HID + g * 32 + i * 4);
      wA[q][4 * n + 0] = wv.x; wA[q][4 * n + 1] = wv.y;
      wA[q][4 * n + 2] = wv.z; wA[q][4 * n + 3] = wv.w;
    }
#pragma unroll
  for (int q = 0; q < 4; ++q)
#pragma unroll
    for (int i = 0; i < 32; ++i) PIN(wA[q][i]);
  if (tid < HID) hl[0][tid] = 0.0f;
  float c = 0.0f;
  int cur = 0;
  bool isg = (g == 2);
  uint16_t pcur = px[((size_t)(T_SEQ - 1) * BATCH + b) * G4 + j];
  __syncthreads();
  for (int t = T_SEQ - 1; t >= 0; --t) {
    int tn = t > 0 ? t - 1 : 0;
    uint16_t pnext = px[((size_t)tn * BATCH + b) * G4 + j];
    const float4* h4 = (const float4*)hl[cur];
    float a0 = 0.f, a1 = 0.f, a2 = 0.f, a3 = 0.f;
#pragma unroll
    for (int n = 0; n < 8; ++n) {
      float4 hv = h4[hbase + (n ^ rot)];
      a0 = fmaf(wA[0][4 * n + 0], hv.x, a0); a0 = fmaf(wA[0][4 * n + 1], hv.y, a0);
      a0 = fmaf(wA[0][4 * n + 2], hv.z, a0); a0 = fmaf(wA[0][4 * n + 3], hv.w, a0);
      a1 = fmaf(wA[1][4 * n + 0], hv.x, a1); a1 = fmaf(wA[1][4 * n + 1], hv.y, a1);
      a1 = fmaf(wA[1][4 * n + 2], hv.z, a1); a1 = fmaf(wA[1][4 * n + 3], hv.w, a1);
      a2 = fmaf(wA[2][4 * n + 0], hv.x, a2); a2 = fmaf(wA[2][4 * n + 1], hv.y, a2);
      a2 = fmaf(wA[2][4 * n + 2], hv.z, a2); a2 = fmaf(wA[2][4 * n + 3], hv.w, a2);
      a3 = fmaf(wA[3][4 * n + 0], hv.x, a3); a3 = fmaf(wA[3][4 * n + 1], hv.y, a3);
      a3 = fmaf(wA[3][4 * n + 2], hv.z, a3); a3 = fmaf(wA[3][4 * n + 3], hv.w, a3);
    }
    float pre = quad_reduce4(a0, a1, a2, a3, g) + bf2f(pcur);
    float act = gate_act(pre, isg);
    float af = dppq<0x55>(act);   // quad lane 1 (f)
    float ag = dppq<0xAA>(act);   // quad lane 2 (g)
    float ao = dppq<0xFF>(act);   // quad lane 3 (o)
    if (g == 0) {
      c = af * c + act * ag;
      float h = ao * tanhfast(c);
      hl[cur ^ 1][u] = h;
      gx[((size_t)t * BATCH + b) * HID + u] = f2bf(h);
    }
    cur ^= 1;
    pcur = pnext;
    __syncthreads();
  }
}

// ---------- kernel 4: fused inference — slice-split stages, weights pinned ----------
__global__ __launch_bounds__(512, 1) void k_inf(
    const uint16_t* __restrict__ gx, const float* __restrict__ eps,
    const float* __restrict__ Wih_gz, const float* __restrict__ Whh_gz,
    const float* __restrict__ bih_gz, const float* __restrict__ bhh_gz,
    const float* __restrict__ W0, const float* __restrict__ b0,
    const float* __restrict__ Wm, const float* __restrict__ bm,
    const float* __restrict__ Wv, const float* __restrict__ bv,
    float* __restrict__ zbuf, float* __restrict__ out_mean,
    float* __restrict__ out_logvar, float* __restrict__ out_z) {
  __shared__ __align__(128) float gxl[HID];
  __shared__ __align__(128) float gzl[2][HID];
  __shared__ __align__(128) float hvec[16 * 12];   // padded: h[8m+k] at [12m+k] (bank-spread)
  __shared__ __align__(128) float zl[ZD];
  int tid = threadIdx.x, b = blockIdx.x;
  // ---- stage A layout: quad (u, gate g), 32-slice of [z(16)|h(128)] per lane ----
  int u = tid >> 2, g = tid & 3;
  int j = g * HID + u;
  int rot = g << 1, hbase = g << 3;
  float wA[4][32];
  float4 wz[4];
#pragma unroll
  for (int q = 0; q < 4; ++q) {
#pragma unroll
    for (int n = 0; n < 8; ++n) {
      int i = n ^ rot;
      float4 wv = *(const float4*)(Whh_gz + ((size_t)(q * HID + u)) * HID + g * 32 + i * 4);
      wA[q][4 * n + 0] = wv.x; wA[q][4 * n + 1] = wv.y;
      wA[q][4 * n + 2] = wv.z; wA[q][4 * n + 3] = wv.w;
    }
    wz[q] = *(const float4*)(Wih_gz + (size_t)(q * HID + u) * ZD + g * 4);
  }
#pragma unroll
  for (int q = 0; q < 4; ++q) {
#pragma unroll
    for (int i = 0; i < 32; ++i) PIN(wA[q][i]);
    PIN(wz[q].x); PIN(wz[q].y); PIN(wz[q].z); PIN(wz[q].w);
  }
  float bzr = bih_gz[j] + bhh_gz[j];
  // ---- stage B layout: 8-way slice, 2 outputs per thread ----
  int sB = tid & 7, uB = (tid >> 3) << 1;
  float w0a[32], w0b[32];
#pragma unroll
  for (int n = 0; n < 8; ++n) {
    int i = n ^ sB;
    float4 va = *(const float4*)(W0 + (size_t)uB * 256 + sB * 32 + i * 4);
    float4 vb = *(const float4*)(W0 + (size_t)(uB + 1) * 256 + sB * 32 + i * 4);
    w0a[4 * n + 0] = va.x; w0a[4 * n + 1] = va.y; w0a[4 * n + 2] = va.z; w0a[4 * n + 3] = va.w;
    w0b[4 * n + 0] = vb.x; w0b[4 * n + 1] = vb.y; w0b[4 * n + 2] = vb.z; w0b[4 * n + 3] = vb.w;
  }
#pragma unroll
  for (int i = 0; i < 32; ++i) { PIN(w0a[i]); PIN(w0b[i]); }
  float b0a = b0[uB], b0b = b0[uB + 1];
  // ---- stage C layout: 32 lanes per output o; lanes 0-15 mean, 16-31 logvar ----
  int o = tid >> 5, lo = tid & 31;
  float wmr[8];
  {
    const float* Wsel = (lo < 16) ? (Wm + (size_t)o * HID + (lo & 15) * 8)
                                  : (Wv + (size_t)o * HID + (lo & 15) * 8);
#pragma unroll
    for (int i = 0; i < 8; ++i) wmr[i] = Wsel[i];
  }
  float bmr = bm[o], bvr = bv[o];
  float czr = 0.0f;
  int cur = 0;
  bool isg = (g == 2);
  if (tid < HID) {
    gzl[0][tid] = 0.0f;
    gxl[tid] = bf2f(gx[(size_t)b * HID + tid]);
  }
  float epcur = (lo == 0) ? eps[(size_t)b * ZD + o] : 0.0f;
  __syncthreads();
  for (int t = 0; t < T_SEQ; ++t) {
    int tn = (t < T_SEQ - 1) ? t + 1 : t;
    float gxnext = (tid < HID) ? bf2f(gx[((size_t)tn * BATCH + b) * HID + tid]) : 0.0f;
    float epnext = (lo == 0) ? eps[((size_t)tn * BATCH + b) * ZD + o] : 0.0f;
    // ---- stage B: h = tanh([gx, gz] @ W0.T + b0), 8-way slice + 8-lane all-reduce ----
    {
      const float4* seg = (sB < 4) ? ((const float4*)gxl + (sB << 3))
                                   : ((const float4*)(gzl[cur]) + ((sB - 4) << 3));
      float pa = 0.f, pb = 0.f;
#pragma unroll
      for (int n = 0; n < 8; ++n) {
        float4 v = seg[n ^ sB];
        pa = fmaf(w0a[4 * n + 0], v.x, pa); pa = fmaf(w0a[4 * n + 1], v.y, pa);
        pa = fmaf(w0a[4 * n + 2], v.z, pa); pa = fmaf(w0a[4 * n + 3], v.w, pa);
        pb = fmaf(w0b[4 * n + 0], v.x, pb); pb = fmaf(w0b[4 * n + 1], v.y, pb);
        pb = fmaf(w0b[4 * n + 2], v.z, pb); pb = fmaf(w0b[4 * n + 3], v.w, pb);
      }
      pa += dppq<0xB1>(pa); pa += dppq<0x4E>(pa); pa += swzx<0x101F>(pa);
      pb += dppq<0xB1>(pb); pb += dppq<0x4E>(pb); pb += swzx<0x101F>(pb);
      if (sB == 0) {
        hvec[((uB >> 3) * 12) + (uB & 7)] = tanhfast(pa + b0a);
        int u1 = uB + 1;
        hvec[((u1 >> 3) * 12) + (u1 & 7)] = tanhfast(pb + b0b);
      }
    }
    __syncthreads();  // b1
    // ---- stage C: mean/logvar/z fused, weights in VGPRs ----
    {
      int m = lo & 15;
      const float4* hh = (const float4*)(hvec + m * 12);
      float4 h0 = hh[0], h1 = hh[1];
      float p = wmr[0] * h0.x + wmr[1] * h0.y + wmr[2] * h0.z + wmr[3] * h0.w +
                wmr[4] * h1.x + wmr[5] * h1.y + wmr[6] * h1.z + wmr[7] * h1.w;
      p += dppq<0xB1>(p);
      p += dppq<0x4E>(p);
      p += swzx<0x101F>(p);
      p += swzx<0x201F>(p);
      float other = swzx<0x401F>(p);   // lanes 0-15 get logvar sum, 16-31 get mean sum
      if (lo == 0) {
        float mean = p + bmr;
        float lv = other + bvr;
        float zv = epcur * __expf(0.5f * lv) + mean;
        zl[o] = zv;
        out_mean[((size_t)b * ZD + o) * T_SEQ + t] = mean;
        out_logvar[((size_t)b * ZD + o) * T_SEQ + t] = lv;
        out_z[((size_t)b * ZD + o) * T_SEQ + t] = zv;
        zbuf[((size_t)t * BATCH + b) * ZD + o] = zv;
      }
    }
    __syncthreads();  // b2
    // ---- stage A: g_z LSTM cell, slice-split quad + butterfly reduce ----
    {
      float4 zv = ((const float4*)zl)[g];
      float a0 = wz[0].x * zv.x; a0 = fmaf(wz[0].y, zv.y, a0);
      a0 = fmaf(wz[0].z, zv.z, a0); a0 = fmaf(wz[0].w, zv.w, a0);
      float a1 = wz[1].x * zv.x; a1 = fmaf(wz[1].y, zv.y, a1);
      a1 = fmaf(wz[1].z, zv.z, a1); a1 = fmaf(wz[1].w, zv.w, a1);
      float a2 = wz[2].x * zv.x; a2 = fmaf(wz[2].y, zv.y, a2);
      a2 = fmaf(wz[2].z, zv.z, a2); a2 = fmaf(wz[2].w, zv.w, a2);
      float a3 = wz[3].x * zv.x; a3 = fmaf(wz[3].y, zv.y, a3);
      a3 = fmaf(wz[3].z, zv.z, a3); a3 = fmaf(wz[3].w, zv.w, a3);
      const float4* h4 = (const float4*)gzl[cur];
#pragma unroll
      for (int n = 0; n < 8; ++n) {
        float4 hv = h4[hbase + (n ^ rot)];
        a0 = fmaf(wA[0][4 * n + 0], hv.x, a0); a0 = fmaf(wA[0][4 * n + 1], hv.y, a0);
        a0 = fmaf(wA[0][4 * n + 2], hv.z, a0); a0 = fmaf(wA[0][4 * n + 3], hv.w, a0);
        a1 = fmaf(wA[1][4 * n + 0], hv.x, a1); a1 = fmaf(wA[1][4 * n + 1], hv.y, a1);
        a1 = fmaf(wA[1][4 * n + 2], hv.z, a1); a1 = fmaf(wA[1][4 * n + 3], hv.w, a1);
        a2 = fmaf(wA[2][4 * n + 0], hv.x, a2); a2 = fmaf(wA[2][4 * n + 1], hv.y, a2);
        a2 = fmaf(wA[2][4 * n + 2], hv.z, a2); a2 = fmaf(wA[2][4 * n + 3], hv.w, a2);
        a3 = fmaf(wA[3][4 * n + 0], hv.x, a3); a3 = fmaf(wA[3][4 * n + 1], hv.y, a3);
        a3 = fmaf(wA[3][4 * n + 2], hv.z, a3); a3 = fmaf(wA[3][4 * n + 3], hv.w, a3);
      }
      float pre = quad_reduce4(a0, a1, a2, a3, g) + bzr;
      float act = gate_act(pre, isg);
      float af = dppq<0x55>(act);
      float ag = dppq<0xAA>(act);
      float ao = dppq<0xFF>(act);
      if (g == 0) {
        czr = af * czr + act * ag;
        gzl[cur ^ 1][u] = ao * tanhfast(czr);
      }
      if (tid < HID) gxl[tid] = gxnext;
    }
    epcur = epnext;
    cur ^= 1;
    __syncthreads();  // b3
  }
}

// ---------- kernel 5: decoder LSTM — slice-split quad, weights pinned ----------
__global__ __launch_bounds__(512, 1) void k_dec(
    const float* __restrict__ zbuf, const float* __restrict__ Wih_h,
    const float* __restrict__ Whh_h, const float* __restrict__ bih,
    const float* __restrict__ bhh, uint16_t* __restrict__ hdec) {
  __shared__ __align__(128) float hl[2][HID];
  __shared__ __align__(128) float zls[2][ZD];
  int tid = threadIdx.x, b = blockIdx.x;
  int u = tid >> 2, g = tid & 3;
  int j = g * HID + u;
  int rot = g << 1, hbase = g << 3;
  float wA[4][32];
  float4 wz[4];
#pragma unroll
  for (int q = 0; q < 4; ++q) {
#pragma unroll
    for (int n = 0; n < 8; ++n) {
      int i = n ^ rot;
      float4 wv = *(const float4*)(Whh_h + ((size_t)(q * HID + u)) * HID + g * 32 + i * 4);
      wA[q][4 * n + 0] = wv.x; wA[q][4 * n + 1] = wv.y;
      wA[q][4 * n + 2] = wv.z; wA[q][4 * n + 3] = wv.w;
    }
    wz[q] = *(const float4*)(Wih_h + (size_t)(q * HID + u) * ZD + g * 4);
  }
#pragma unroll
  for (int q = 0; q < 4; ++q) {
#pragma unroll
    for (int i = 0; i < 32; ++i) PIN(wA[q][i]);
    PIN(wz[q].x); PIN(wz[q].y); PIN(wz[q].z); PIN(wz[q].w);
  }
  float bz = bih[j] + bhh[j];
  if (tid < HID) hl[0][tid] = 0.0f;
  if (tid < ZD) zls[0][tid] = zbuf[(size_t)b * ZD + tid];
  float c = 0.0f;
  int cur = 0;
  bool isg = (g == 2);
  __syncthreads();
  for (int t = 0; t < T_SEQ; ++t) {
    int tn = (t < T_SEQ - 1) ? t + 1 : t;
    float znext = (tid < ZD) ? zbuf[((size_t)tn * BATCH + b) * ZD + tid] : 0.0f;
    float4 zv = ((const float4*)zls[cur])[g];
    float a0 = wz[0].x * zv.x; a0 = fmaf(wz[0].y, zv.y, a0);
    a0 = fmaf(wz[0].z, zv.z, a0); a0 = fmaf(wz[0].w, zv.w, a0);
    float a1 = wz[1].x * zv.x; a1 = fmaf(wz[1].y, zv.y, a1);
    a1 = fmaf(wz[1].z, zv.z, a1); a1 = fmaf(wz[1].w, zv.w, a1);
    float a2 = wz[2].x * zv.x; a2 = fmaf(wz[2].y, zv.y, a2);
    a2 = fmaf(wz[2].z, zv.z, a2); a2 = fmaf(wz[2].w, zv.w, a2);
    float a3 = wz[3].x * zv.x; a3 = fmaf(wz[3].y, zv.y, a3);
    a3 = fmaf(wz[3].z, zv.z, a3); a3 = fmaf(wz[3].w, zv.w, a3);
    const float4* h4 = (const float4*)hl[cur];
#pragma unroll
    for (int n = 0; n < 8; ++n) {
      float4 hv = h4[hbase + (n ^ rot)];
      a0 = fmaf(wA[0][4 * n + 0], hv.x, a0); a0 = fmaf(wA[0][4 * n + 1], hv.y, a0);
      a0 = fmaf(wA[0][4 * n + 2], hv.z, a0); a0 = fmaf(wA[0][4 * n + 3], hv.w, a0);
      a1 = fmaf(wA[1][4 * n + 0], hv.x, a1); a1 = fmaf(wA[1][4 * n + 1], hv.y, a1);
      a1 = fmaf(wA[1][4 * n + 2], hv.z, a1); a1 = fmaf(wA[1][4 * n + 3], hv.w, a1);
      a2 = fmaf(wA[2][4 * n + 0], hv.x, a2); a2 = fmaf(wA[2][4 * n + 1], hv.y, a2);
      a2 = fmaf(wA[2][4 * n + 2], hv.z, a2); a2 = fmaf(wA[2][4 * n + 3], hv.w, a2);
      a3 = fmaf(wA[3][4 * n + 0], hv.x, a3); a3 = fmaf(wA[3][4 * n + 1], hv.y, a3);
      a3 = fmaf(wA[3][4 * n + 2], hv.z, a3); a3 = fmaf(wA[3][4 * n + 3], hv.w, a3);
    }
    float pre = quad_reduce4(a0, a1, a2, a3, g) + bz;
    float act = gate_act(pre, isg);
    float af = dppq<0x55>(act);
    float ag = dppq<0xAA>(act);
    float ao = dppq<0xFF>(act);
    if (g == 0) {
      c = af * c + act * ag;
      float h = ao * tanhfast(c);
      hl[cur ^ 1][u] = h;
      hdec[((size_t)t * BATCH + b) * HID + u] = f2bf(h);
    }
    if (tid < ZD) zls[cur ^ 1][tid] = znext;
    cur ^= 1;
    __syncthreads();
  }
}

// ---------- kernel 6: y = exp(hdec @ Wy.T + by), output (B, 257, T) ----------
__global__ __launch_bounds__(256) void k_y(
    const uint16_t* __restrict__ hdec, const float* __restrict__ wyT,
    const float* __restrict__ by, float* __restrict__ out_y) {
  __shared__ __align__(16) float hl[HID * 65];
  int tid = threadIdx.x;
  int t0 = blockIdx.x * 64, b = blockIdx.y;
  {
    int uu = tid & 127, tg = tid >> 7;
    for (int tt = tg; tt < 64; tt += 2)
      hl[uu * 65 + tt] = bf2f(hdec[((size_t)(t0 + tt) * BATCH + b) * HID + uu]);
  }
  __syncthreads();
  int w = __builtin_amdgcn_readfirstlane(tid >> 6);
  int lane = tid & 63;
  for (int p = 0; p < 4; ++p) {
    int d0 = w * 16 + p * 64;
    float acc[16];
#pragma unroll
    for (int i = 0; i < 16; ++i) acc[i] = by[d0 + i];
    for (int uu = 0; uu < HID; ++uu) {
      float hv = hl[uu * 65 + lane];
      const float* wrow = wyT + (size_t)uu * XD + d0;
#pragma unroll
      for (int i = 0; i < 16; ++i) acc[i] = fmaf(wrow[i], hv, acc[i]);
    }
#pragma unroll
    for (int i = 0; i < 16; ++i)
      out_y[((size_t)b * XD + d0 + i) * T_SEQ + t0 + lane] = __expf(acc[i]);
  }
  if (w == 0) {  // d = 256 tail
    float acc = by[256];
    for (int uu = 0; uu < HID; ++uu)
      acc = fmaf(wyT[(size_t)uu * XD + 256], hl[uu * 65 + lane], acc);
    out_y[((size_t)b * XD + 256) * T_SEQ + t0 + lane] = __expf(acc);
  }
}

extern "C" void kernel_launch(void* const* d_in, const int* in_sizes, int n_in,
                              void* d_out, int out_size, void* d_ws, size_t ws_size,
                              hipStream_t stream) {
  const float* x      = (const float*)d_in[0];
  const float* eps    = (const float*)d_in[1];
  const float* Wih_gx = (const float*)d_in[2];
  const float* Whh_gx = (const float*)d_in[3];
  const float* bih_gx = (const float*)d_in[4];
  const float* bhh_gx = (const float*)d_in[5];
  const float* Wih_gz = (const float*)d_in[6];
  const float* Whh_gz = (const float*)d_in[7];
  const float* bih_gz = (const float*)d_in[8];
  const float* bhh_gz = (const float*)d_in[9];
  const float* W0     = (const float*)d_in[10];
  const float* b0     = (const float*)d_in[11];
  const float* Wm     = (const float*)d_in[12];
  const float* bm     = (const float*)d_in[13];
  const float* Wv     = (const float*)d_in[14];
  const float* bv     = (const float*)d_in[15];
  const float* Wih_h  = (const float*)d_in[16];
  const float* Whh_h  = (const float*)d_in[17];
  const float* bih_h  = (const float*)d_in[18];
  const float* bhh_h  = (const float*)d_in[19];
  const float* Wy     = (const float*)d_in[20];
  const float* by     = (const float*)d_in[21];

  char* ws = (char*)d_ws;
  float*    wT   = (float*)(ws + 0);                       // 257*512 f32   = 526,336 B
  float*    wyT  = (float*)(ws + 526336);                  // 128*257 f32   = 131,584 B
  uint16_t* px   = (uint16_t*)(ws + (1u << 20));           // bf16 T*B*512  = 134,217,728 B
  uint16_t* gx   = (uint16_t*)(ws + 135266304);            // bf16 T*B*128  =  33,554,432 B
  float*    zbuf = (float*)(ws + 168820736);               // f32  T*B*16   =   8,388,608 B
  uint16_t* hdec = (uint16_t*)(ws + 177209344);            // bf16 T*B*128  =  33,554,432 B

  float* out_y      = (float*)d_out;                         // (B,257,T)
  float* out_mean   = out_y + (size_t)BATCH * XD * T_SEQ;    // (B,16,T)
  float* out_logvar = out_mean + (size_t)BATCH * ZD * T_SEQ;
  float* out_z      = out_logvar + (size_t)BATCH * ZD * T_SEQ;

  k_prep<<<dim3(643), dim3(256), 0, stream>>>(Wih_gx, Wy, wT, wyT);
  k_proj<<<dim3(8, 256), dim3(256), 0, stream>>>(x, wT, bih_gx, bhh_gx, px);
  k_lstm_gx<<<dim3(256), dim3(512), 0, stream>>>(px, Whh_gx, gx);
  k_inf<<<dim3(256), dim3(512), 0, stream>>>(gx, eps, Wih_gz, Whh_gz, bih_gz, bhh_gz,
                                             W0, b0, Wm, bm, Wv, bv,
                                             zbuf, out_mean, out_logvar, out_z);
  k_dec<<<dim3(256), dim3(512), 0, stream>>>(zbuf, Wih_h, Whh_h, bih_h, bhh_h, hdec);
  k_y<<<dim3(8, 256), dim3(256), 0, stream>>>(hdec, wyT, by, out_y);
}